// Round 2
// baseline (1357.991 us; speedup 1.0000x reference)
//
#include <hip/hip_runtime.h>
#include <stdint.h>

#define V3 (48*48*48)   // 110592 voxels per channel
#define BATCH 8

typedef __bf16 bf16x8 __attribute__((ext_vector_type(8)));
typedef float  f32x4  __attribute__((ext_vector_type(4)));

__device__ __forceinline__ unsigned short f2bf(float f) {
  uint32_t u = __float_as_uint(f);
  u += 0x7fffu + ((u >> 16) & 1u);   // round-to-nearest-even
  return (unsigned short)(u >> 16);
}

// async 16B global->LDS; LDS dest = wave-uniform base + lane*16
#define GLDS16(gp, lp)                                                         \
  __builtin_amdgcn_global_load_lds(                                            \
      (const __attribute__((address_space(1))) void*)(gp),                     \
      (__attribute__((address_space(3))) void*)(lp), 16, 0, 0)

// ---------------------------------------------------------------- stats ----
// one block per (b,c): mu, rstd over 48^3; block 0 also zeroes the zero page.
__global__ __launch_bounds__(1024)
void stats_kernel(const float* __restrict__ x, float* __restrict__ mu,
                  float* __restrict__ rstd, float4* __restrict__ zpage) {
  if (blockIdx.x == 0 && threadIdx.x < 64) {
    float4 z; z.x = 0.f; z.y = 0.f; z.z = 0.f; z.w = 0.f;
    zpage[threadIdx.x] = z;
  }
  const int bc = blockIdx.x;  // 0..255
  const float4* p = reinterpret_cast<const float4*>(x + (size_t)bc * V3);
  float s = 0.f, s2 = 0.f;
  for (int i = threadIdx.x; i < V3 / 4; i += 1024) {   // 27 exact iterations
    float4 v = p[i];
    s  += (v.x + v.y) + (v.z + v.w);
    s2 += (v.x * v.x + v.y * v.y) + (v.z * v.z + v.w * v.w);
  }
  for (int o = 32; o; o >>= 1) { s += __shfl_down(s, o); s2 += __shfl_down(s2, o); }
  __shared__ float red[32];
  const int wave = threadIdx.x >> 6, lane = threadIdx.x & 63;
  if (lane == 0) { red[wave] = s; red[16 + wave] = s2; }
  __syncthreads();
  if (threadIdx.x == 0) {
    float S1 = 0.f, S2 = 0.f;
#pragma unroll
    for (int i = 0; i < 16; ++i) { S1 += red[i]; S2 += red[16 + i]; }
    float m = S1 / (float)V3;
    float var = S2 / (float)V3 - m * m;
    mu[bc] = m;
    rstd[bc] = rsqrtf(var + 1e-5f);
  }
}

// --------------------------------------------------------------- repack ----
// x [b][c][d][h][w] fp32 -> xcl [b][d][h][w][c] bf16 (channels-last)
__global__ __launch_bounds__(256)
void repack_kernel(const float* __restrict__ x, unsigned short* __restrict__ xcl) {
  const int bid = blockIdx.x;            // B*48*48 blocks, one (b,d,h) row each
  const int h = bid % 48;
  const int d = (bid / 48) % 48;
  const int b = bid / (48 * 48);
  __shared__ float tile[32][48];
  const float* src = x + (size_t)b * 32 * V3 + (size_t)(d * 48 + h) * 48;
  for (int i = threadIdx.x; i < 32 * 48; i += 256) {
    int c = i / 48, w = i - c * 48;
    tile[c][w] = src[(size_t)c * V3 + w];
  }
  __syncthreads();
  const int i = threadIdx.x;
  if (i < 48 * 4) {
    const int w = i >> 2, pp = i & 3;
    alignas(16) unsigned short pk[8];
#pragma unroll
    for (int j = 0; j < 8; ++j) pk[j] = f2bf(tile[pp * 8 + j][w]);
    *reinterpret_cast<uint4*>(
        &xcl[((size_t)b * V3 + (size_t)(d * 48 + h) * 48 + w) * 32 + pp * 8]) =
        *reinterpret_cast<const uint4*>(pk);
  }
}

// ---------------------------------------------------------------- wprep ----
// w1 : [b][tap(27)][mt(4)][lane(64)][8]   lane=(q*16+n) -> cout=mt*16+n, cin=q*8+j
// w23: [b][kc(2)][tap(27)][mt(4)][lane(64)][8]  cout rows 0-31 gamma, 32-63 beta
__global__ __launch_bounds__(256)
void wprep_kernel(const int* __restrict__ y, const float* __restrict__ Wsh,
                  const float* __restrict__ Wg, const float* __restrict__ Wb,
                  unsigned short* __restrict__ w1, unsigned short* __restrict__ w23) {
  const int N1 = BATCH * 27 * 4 * 64 * 8;       // 442368
  const int N2 = BATCH * 2 * 27 * 4 * 64 * 8;   // 884736
  int idx = blockIdx.x * 256 + threadIdx.x;
  if (idx < N1) {
    const int j = idx & 7;
    const int lane = (idx >> 3) & 63;
    const int mt = (idx >> 9) & 3;
    const int tap = (idx >> 11) % 27;
    const int b = idx / (27 << 11);
    const int q = lane >> 4, n = lane & 15;
    const int cout = mt * 16 + n, cin = q * 8 + j;
    const int cls = y[b];
    w1[idx] = f2bf(Wsh[((size_t)((cls * 64 + cout) * 32 + cin)) * 27 + tap]);
  } else if (idx < N1 + N2) {
    const int t = idx - N1;
    const int b = t / 110592;
    const int r1 = t - b * 110592;
    const int kc = r1 / 55296;
    const int r2 = r1 - kc * 55296;
    const int tap = r2 >> 11;
    const int r3 = r2 & 2047;
    const int mt = r3 >> 9;
    const int lane = (r3 >> 3) & 63;
    const int j = r3 & 7;
    const int q = lane >> 4, n = lane & 15;
    const int cout = mt * 16 + n, cin = kc * 32 + q * 8 + j;
    const int cls = y[b];
    float v = (cout < 32) ? Wg[((size_t)((cls * 32 + cout) * 64 + cin)) * 27 + tap]
                          : Wb[((size_t)((cls * 32 + (cout - 32)) * 64 + cin)) * 27 + tap];
    w23[t] = f2bf(v);
  }
}

// ------------------------------------------------------- conv tile geometry -
// Tile 6d x 6h x 16w, 6 waves (384 thr), wave = output d-slice.
// Halo 8d x 8h x 18w = 1152 voxels; LDS plane-major, 16B chunks:
//   slot(ld,pp,lh,lw) = ((ld*4+pp)*8+lh)*18 + lw          (4608 slots)
// Planes 0..5 = slots [0,3456) (all dz=0 taps), planes 6..7 = [3456,4608).
// Staging: 12 loads/thread, slot j = tid + k*384; k<9 <=> j<3456 (group A).
// sched_barrier(0) between groups pins VMEM issue order so vmcnt(3) is exact.
// LDS = 73728 B: 2 blocks/CU = 12 waves/CU (3/SIMD).

#define STAGE_RANGE(K0, K1, SRC_EXPR)                                          \
  do {                                                                         \
    _Pragma("unroll") for (int k = (K0); k < (K1); ++k) {                      \
      const int j = tid + k * 384;                                             \
      const int ld_ = j / 576;                                                 \
      const int r = j - ld_ * 576;                                             \
      const int pp = r / 144;                                                  \
      const int r2 = r - pp * 144;                                             \
      const int lh = r2 / 18;                                                  \
      const int lw = r2 - lh * 18;                                             \
      const int d = d0 + ld_ - 1, h = h0 + lh - 1, w = w0 + lw - 1;            \
      const bool ok = (unsigned)d < 48u && (unsigned)h < 48u && (unsigned)w < 48u; \
      const void* gp = ok ? (const void*)(SRC_EXPR)                            \
                          : (const void*)((const char*)zpage + lane * 16);     \
      GLDS16(gp, &lds[(size_t)(j - lane) * 8]);                                \
    }                                                                          \
  } while (0)

#define STAGE12(SRC_EXPR)                                                      \
  do {                                                                         \
    STAGE_RANGE(0, 9, SRC_EXPR);                                               \
    __builtin_amdgcn_sched_barrier(0);  /* pin group A before group B */       \
    STAGE_RANGE(9, 12, SRC_EXPR);                                              \
  } while (0)

// dz-group compute: 9 fully-unrolled taps (compile-time dy/dx).
#define COMPUTE_DZ(DZ, WB)                                                     \
  do {                                                                         \
    const int pb_ = ((wave + (DZ)) * 4 + q) * 144 + n;                         \
    __builtin_amdgcn_s_setprio(1);                                             \
    _Pragma("unroll") for (int t9 = 0; t9 < 9; ++t9) {                         \
      const int dy_ = t9 / 3, dx_ = t9 - dy_ * 3;                              \
      bf16x8 aw[4];                                                            \
      _Pragma("unroll") for (int mt = 0; mt < 4; ++mt)                         \
        aw[mt] = *reinterpret_cast<const bf16x8*>(                             \
            &(WB)[(((DZ) * 9 + t9) * 4 + mt) * 512]);                          \
      _Pragma("unroll") for (int g = 0; g < 6; ++g) {                          \
        const bf16x8 bv = *reinterpret_cast<const bf16x8*>(                    \
            &lds[(size_t)(pb_ + (g + dy_) * 18 + dx_) * 8]);                   \
        _Pragma("unroll") for (int mt = 0; mt < 4; ++mt)                       \
          acc[g][mt] = __builtin_amdgcn_mfma_f32_16x16x32_bf16(                \
              aw[mt], bv, acc[g][mt], 0, 0, 0);                                \
      }                                                                        \
    }                                                                          \
    __builtin_amdgcn_s_setprio(0);                                             \
  } while (0)

#define WAIT_VM(N)                                                             \
  asm volatile("s_waitcnt vmcnt(" #N ")" ::: "memory")

// ---------------------------------------------------------------- conv1 ----
// actv = relu(conv3x3x3(x; 32->64)), channels-last bf16 out.
__global__ __launch_bounds__(384, 3)
void conv1_kernel(const unsigned short* __restrict__ xcl,
                  const unsigned short* __restrict__ w1,
                  const int* __restrict__ y, const float* __restrict__ bsh,
                  unsigned short* __restrict__ actv,
                  const float4* __restrict__ zpage) {
  const int d0 = (blockIdx.y >> 3) * 6;
  const int h0 = (blockIdx.y & 7) * 6;
  const int w0 = blockIdx.x * 16;
  const int b = blockIdx.z;

  __shared__ unsigned short lds[4608 * 8];   // 73728 B

  const int tid = threadIdx.x;
  const int lane = tid & 63;
  const int wave = tid >> 6;                 // 0..5 = output d-slice
  const int q = lane >> 4, n = lane & 15;

  const unsigned short* xb = xcl + (size_t)b * V3 * 32;
  STAGE12(xb + ((size_t)((d * 48 + h) * 48 + w)) * 32 + pp * 8);

  f32x4 acc[6][4];
#pragma unroll
  for (int g = 0; g < 6; ++g)
#pragma unroll
    for (int mt = 0; mt < 4; ++mt) acc[g][mt] = (f32x4){0.f, 0.f, 0.f, 0.f};

  const unsigned short* wb = w1 + (size_t)b * 55296 + lane * 8;

  WAIT_VM(3);            // group A (planes 0..5) resident; B still in flight
  __builtin_amdgcn_s_barrier();
  COMPUTE_DZ(0, wb);     // dz=0 touches only planes 0..5
  WAIT_VM(0);
  __builtin_amdgcn_s_barrier();
  COMPUTE_DZ(1, wb);
  COMPUTE_DZ(2, wb);

  const int cls = y[b];
  const int od = d0 + wave, ow = w0 + n;
#pragma unroll
  for (int g = 0; g < 6; ++g) {
    const int oh = h0 + g;
    const size_t vg = (size_t)(od * 48 + oh) * 48 + ow;
#pragma unroll
    for (int mt = 0; mt < 4; ++mt) {
      const int c0 = mt * 16 + q * 4;
      ushort4 pk;
      pk.x = f2bf(fmaxf(acc[g][mt][0] + bsh[cls * 64 + c0 + 0], 0.f));
      pk.y = f2bf(fmaxf(acc[g][mt][1] + bsh[cls * 64 + c0 + 1], 0.f));
      pk.z = f2bf(fmaxf(acc[g][mt][2] + bsh[cls * 64 + c0 + 2], 0.f));
      pk.w = f2bf(fmaxf(acc[g][mt][3] + bsh[cls * 64 + c0 + 3], 0.f));
      *reinterpret_cast<ushort4*>(&actv[((size_t)b * V3 + vg) * 64 + c0]) = pk;
    }
  }
}

// ---------------------------------------------------------------- conv2 ----
// gamma/beta = conv3x3x3(actv; 64->32 each, stacked 64 couts), fused epilogue
// out = (x-mu)*rstd*(1+gamma) + beta.  2 kc passes over cin halves.
__global__ __launch_bounds__(384, 3)
void conv2_kernel(const unsigned short* __restrict__ actv,
                  const unsigned short* __restrict__ w23,
                  const int* __restrict__ y, const float* __restrict__ bgm,
                  const float* __restrict__ bbt, const float* __restrict__ x,
                  const float* __restrict__ mu, const float* __restrict__ rstd,
                  float* __restrict__ out, const float4* __restrict__ zpage) {
  const int d0 = (blockIdx.y >> 3) * 6;
  const int h0 = (blockIdx.y & 7) * 6;
  const int w0 = blockIdx.x * 16;
  const int b = blockIdx.z;

  __shared__ unsigned short lds[4608 * 8];   // 73728 B

  const int tid = threadIdx.x;
  const int lane = tid & 63;
  const int wave = tid >> 6;
  const int q = lane >> 4, n = lane & 15;

  f32x4 acc[6][4];
#pragma unroll
  for (int g = 0; g < 6; ++g)
#pragma unroll
    for (int mt = 0; mt < 4; ++mt) acc[g][mt] = (f32x4){0.f, 0.f, 0.f, 0.f};

  const unsigned short* ab = actv + (size_t)b * V3 * 64;

  for (int kc = 0; kc < 2; ++kc) {
    if (kc) { __syncthreads(); }   // all reads of pass-0 LDS retired
    STAGE12(ab + ((size_t)((d * 48 + h) * 48 + w)) * 64 + kc * 32 + pp * 8);

    const unsigned short* wb =
        w23 + (size_t)b * 110592 + (size_t)kc * 55296 + lane * 8;

    WAIT_VM(3);
    __builtin_amdgcn_s_barrier();
    COMPUTE_DZ(0, wb);
    WAIT_VM(0);
    __builtin_amdgcn_s_barrier();
    COMPUTE_DZ(1, wb);
    COMPUTE_DZ(2, wb);
  }

  const int cls = y[b];
  const int od = d0 + wave, ow = w0 + n;
#pragma unroll
  for (int g = 0; g < 6; ++g) {
    const int oh = h0 + g;
    const size_t vg = (size_t)(od * 48 + oh) * 48 + ow;
#pragma unroll
    for (int mt = 0; mt < 2; ++mt) {
#pragma unroll
      for (int r = 0; r < 4; ++r) {
        const int c = mt * 16 + q * 4 + r;
        const float gamma = acc[g][mt][r] + bgm[cls * 32 + c];
        const float beta = acc[g][mt + 2][r] + bbt[cls * 32 + c];
        const size_t xi = (size_t)(b * 32 + c) * V3 + vg;
        const float xn = (x[xi] - mu[b * 32 + c]) * rstd[b * 32 + c];
        out[xi] = xn * (1.f + gamma) + beta;
      }
    }
  }
}

// ------------------------------------------------------------------ launch -
extern "C" void kernel_launch(void* const* d_in, const int* in_sizes, int n_in,
                              void* d_out, int out_size, void* d_ws, size_t ws_size,
                              hipStream_t stream) {
  const float* x = (const float*)d_in[0];
  const int* y = (const int*)d_in[1];
  const float* Wsh = (const float*)d_in[2];
  const float* bsh = (const float*)d_in[3];
  const float* Wg = (const float*)d_in[4];
  const float* bg = (const float*)d_in[5];
  const float* Wb = (const float*)d_in[6];
  const float* bb = (const float*)d_in[7];
  float* out = (float*)d_out;

  char* ws = (char*)d_ws;
  unsigned short* xcl  = (unsigned short*)(ws + 0);           // 56,623,104 B
  unsigned short* actv = (unsigned short*)(ws + 56623104);    // 113,246,208 B
  unsigned short* w1   = (unsigned short*)(ws + 169869312);   //    884,736 B
  unsigned short* w23  = (unsigned short*)(ws + 170754048);   //  1,769,472 B
  float* mu    = (float*)(ws + 172523520);                    //      1,024 B
  float* rstd  = (float*)(ws + 172524544);                    //      1,024 B
  float4* zpg  = (float4*)(ws + 172525568);                   //      1,024 B

  stats_kernel<<<256, 1024, 0, stream>>>(x, mu, rstd, zpg);
  repack_kernel<<<BATCH * 48 * 48, 256, 0, stream>>>(x, xcl);
  wprep_kernel<<<(BATCH * 27 * 4 * 64 * 8 * 3 + 255) / 256, 256, 0, stream>>>(
      y, Wsh, Wg, Wb, w1, w23);

  dim3 grid(3, 64, BATCH);   // w:3, (d:8 x h:8):64, b:8
  conv1_kernel<<<grid, 384, 0, stream>>>(xcl, w1, y, bsh, actv, zpg);
  conv2_kernel<<<grid, 384, 0, stream>>>(actv, w23, y, bg, bb, x, mu, rstd, out, zpg);
}

// Round 3
// 647.465 us; speedup vs baseline: 2.0974x; 2.0974x over previous
//
#include <hip/hip_runtime.h>
#include <stdint.h>

#define V3 (48*48*48)   // 110592 voxels per channel
#define BATCH 8

typedef __bf16 bf16x8 __attribute__((ext_vector_type(8)));
typedef float  f32x4  __attribute__((ext_vector_type(4)));

__device__ __forceinline__ unsigned short f2bf(float f) {
  uint32_t u = __float_as_uint(f);
  u += 0x7fffu + ((u >> 16) & 1u);   // round-to-nearest-even
  return (unsigned short)(u >> 16);
}

// async 16B global->LDS; LDS dest = wave-uniform base + lane*16
#define GLDS16(gp, lp)                                                         \
  __builtin_amdgcn_global_load_lds(                                            \
      (const __attribute__((address_space(1))) void*)(gp),                     \
      (__attribute__((address_space(3))) void*)(lp), 16, 0, 0)

// ---------------------------------------------------------------- stats ----
// one block per (b,c): mu, rstd over 48^3; block 0 also zeroes the zero page.
__global__ __launch_bounds__(1024)
void stats_kernel(const float* __restrict__ x, float* __restrict__ mu,
                  float* __restrict__ rstd, float4* __restrict__ zpage) {
  if (blockIdx.x == 0 && threadIdx.x < 64) {
    float4 z; z.x = 0.f; z.y = 0.f; z.z = 0.f; z.w = 0.f;
    zpage[threadIdx.x] = z;
  }
  const int bc = blockIdx.x;  // 0..255
  const float4* p = reinterpret_cast<const float4*>(x + (size_t)bc * V3);
  float s = 0.f, s2 = 0.f;
  for (int i = threadIdx.x; i < V3 / 4; i += 1024) {   // 27 exact iterations
    float4 v = p[i];
    s  += (v.x + v.y) + (v.z + v.w);
    s2 += (v.x * v.x + v.y * v.y) + (v.z * v.z + v.w * v.w);
  }
  for (int o = 32; o; o >>= 1) { s += __shfl_down(s, o); s2 += __shfl_down(s2, o); }
  __shared__ float red[32];
  const int wave = threadIdx.x >> 6, lane = threadIdx.x & 63;
  if (lane == 0) { red[wave] = s; red[16 + wave] = s2; }
  __syncthreads();
  if (threadIdx.x == 0) {
    float S1 = 0.f, S2 = 0.f;
#pragma unroll
    for (int i = 0; i < 16; ++i) { S1 += red[i]; S2 += red[16 + i]; }
    float m = S1 / (float)V3;
    float var = S2 / (float)V3 - m * m;
    mu[bc] = m;
    rstd[bc] = rsqrtf(var + 1e-5f);
  }
}

// --------------------------------------------------------------- repack ----
// x [b][c][d][h][w] fp32 -> xcl [b][d][h][w][c] bf16 (channels-last)
__global__ __launch_bounds__(256)
void repack_kernel(const float* __restrict__ x, unsigned short* __restrict__ xcl) {
  const int bid = blockIdx.x;            // B*48*48 blocks, one (b,d,h) row each
  const int h = bid % 48;
  const int d = (bid / 48) % 48;
  const int b = bid / (48 * 48);
  __shared__ float tile[32][48];
  const float* src = x + (size_t)b * 32 * V3 + (size_t)(d * 48 + h) * 48;
  for (int i = threadIdx.x; i < 32 * 48; i += 256) {
    int c = i / 48, w = i - c * 48;
    tile[c][w] = src[(size_t)c * V3 + w];
  }
  __syncthreads();
  const int i = threadIdx.x;
  if (i < 48 * 4) {
    const int w = i >> 2, pp = i & 3;
    alignas(16) unsigned short pk[8];
#pragma unroll
    for (int j = 0; j < 8; ++j) pk[j] = f2bf(tile[pp * 8 + j][w]);
    *reinterpret_cast<uint4*>(
        &xcl[((size_t)b * V3 + (size_t)(d * 48 + h) * 48 + w) * 32 + pp * 8]) =
        *reinterpret_cast<const uint4*>(pk);
  }
}

// ---------------------------------------------------------------- wprep ----
// w1 : [b][tap(27)][mt(4)][lane(64)][8]   lane=(q*16+n) -> cout=mt*16+n, cin=q*8+j
// w23: [b][kc(2)][tap(27)][mt(4)][lane(64)][8]  cout rows 0-31 gamma, 32-63 beta
__global__ __launch_bounds__(256)
void wprep_kernel(const int* __restrict__ y, const float* __restrict__ Wsh,
                  const float* __restrict__ Wg, const float* __restrict__ Wb,
                  unsigned short* __restrict__ w1, unsigned short* __restrict__ w23) {
  const int N1 = BATCH * 27 * 4 * 64 * 8;       // 442368
  const int N2 = BATCH * 2 * 27 * 4 * 64 * 8;   // 884736
  int idx = blockIdx.x * 256 + threadIdx.x;
  if (idx < N1) {
    const int j = idx & 7;
    const int lane = (idx >> 3) & 63;
    const int mt = (idx >> 9) & 3;
    const int tap = (idx >> 11) % 27;
    const int b = idx / (27 << 11);
    const int q = lane >> 4, n = lane & 15;
    const int cout = mt * 16 + n, cin = q * 8 + j;
    const int cls = y[b];
    w1[idx] = f2bf(Wsh[((size_t)((cls * 64 + cout) * 32 + cin)) * 27 + tap]);
  } else if (idx < N1 + N2) {
    const int t = idx - N1;
    const int b = t / 110592;
    const int r1 = t - b * 110592;
    const int kc = r1 / 55296;
    const int r2 = r1 - kc * 55296;
    const int tap = r2 >> 11;
    const int r3 = r2 & 2047;
    const int mt = r3 >> 9;
    const int lane = (r3 >> 3) & 63;
    const int j = r3 & 7;
    const int q = lane >> 4, n = lane & 15;
    const int cout = mt * 16 + n, cin = kc * 32 + q * 8 + j;
    const int cls = y[b];
    float v = (cout < 32) ? Wg[((size_t)((cls * 32 + cout) * 64 + cin)) * 27 + tap]
                          : Wb[((size_t)((cls * 32 + (cout - 32)) * 64 + cin)) * 27 + tap];
    w23[t] = f2bf(v);
  }
}

// ------------------------------------------------------- conv tile geometry -
// Tile 4d x 6h x 16w, 4 waves (256 thr), wave = output d-slice (R0 budget:
// __launch_bounds__(256,2), 55296B LDS, 2 blocks/CU — no register squeeze).
// Halo 6d x 8h x 18w = 864 voxels; LDS PLANE-MAJOR, 16B chunks:
//   slot(ld,pp,lh,lw) = ((ld*4+pp)*8+lh)*18 + lw         (3456 slots)
// Planes 0..3 = slots [0,2304) = staging k 0..8 exactly (j = tid + 256k).
// Planes 4..5 = k 9..13 (k=13 only tid<128). Per-wave B-counts {5,5,4,4}
// -> WAIT_VM(4) guarantees every wave's group-A loads are resident.
// sched_barrier(0) pins group-A VMEM issue before group-B so counting holds.

#define STAGE_K(K0, K1, SRC_EXPR)                                              \
  do {                                                                         \
    _Pragma("unroll") for (int k = (K0); k < (K1); ++k) {                      \
      const int j = tid + k * 256;                                             \
      if (k < 13 || tid < 128) {                                               \
        const int ld_ = j / 576;                                               \
        const int r = j - ld_ * 576;                                           \
        const int pp = r / 144;                                                \
        const int r2 = r - pp * 144;                                           \
        const int lh = r2 / 18;                                                \
        const int lw = r2 - lh * 18;                                           \
        const int d = d0 + ld_ - 1, h = h0 + lh - 1, w = w0 + lw - 1;          \
        const bool ok = (unsigned)d < 48u && (unsigned)h < 48u && (unsigned)w < 48u; \
        const void* gp = ok ? (const void*)(SRC_EXPR)                          \
                            : (const void*)((const char*)zpage + lane * 16);   \
        GLDS16(gp, &lds[(size_t)(j - lane) * 8]);                              \
      }                                                                        \
    }                                                                          \
  } while (0)

#define STAGE14(SRC_EXPR)                                                      \
  do {                                                                         \
    STAGE_K(0, 9, SRC_EXPR);                                                   \
    __builtin_amdgcn_sched_barrier(0);  /* pin group A before group B */       \
    STAGE_K(9, 14, SRC_EXPR);                                                  \
  } while (0)

// dz-group compute: 9 fully-unrolled taps (compile-time dy/dx).
#define COMPUTE_DZ(DZ, WB)                                                     \
  do {                                                                         \
    const int pb_ = ((wave + (DZ)) * 4 + q) * 144 + n;                         \
    __builtin_amdgcn_s_setprio(1);                                             \
    _Pragma("unroll") for (int t9 = 0; t9 < 9; ++t9) {                         \
      const int dy_ = t9 / 3, dx_ = t9 - dy_ * 3;                              \
      bf16x8 aw[4];                                                            \
      _Pragma("unroll") for (int mt = 0; mt < 4; ++mt)                         \
        aw[mt] = *reinterpret_cast<const bf16x8*>(                             \
            &(WB)[(((DZ) * 9 + t9) * 4 + mt) * 512]);                          \
      _Pragma("unroll") for (int g = 0; g < 6; ++g) {                          \
        const bf16x8 bv = *reinterpret_cast<const bf16x8*>(                    \
            &lds[(size_t)(pb_ + (g + dy_) * 18 + dx_) * 8]);                   \
        _Pragma("unroll") for (int mt = 0; mt < 4; ++mt)                       \
          acc[g][mt] = __builtin_amdgcn_mfma_f32_16x16x32_bf16(                \
              aw[mt], bv, acc[g][mt], 0, 0, 0);                                \
      }                                                                        \
    }                                                                          \
    __builtin_amdgcn_s_setprio(0);                                             \
  } while (0)

#define WAIT_VM(N)                                                             \
  asm volatile("s_waitcnt vmcnt(" #N ")" ::: "memory")

// ---------------------------------------------------------------- conv1 ----
// actv = relu(conv3x3x3(x; 32->64)), channels-last bf16 out.
__global__ __launch_bounds__(256, 2)
void conv1_kernel(const unsigned short* __restrict__ xcl,
                  const unsigned short* __restrict__ w1,
                  const int* __restrict__ y, const float* __restrict__ bsh,
                  unsigned short* __restrict__ actv,
                  const float4* __restrict__ zpage) {
  const int d0 = (blockIdx.y >> 3) * 4;
  const int h0 = (blockIdx.y & 7) * 6;
  const int w0 = blockIdx.x * 16;
  const int b = blockIdx.z;

  __shared__ unsigned short lds[3456 * 8];   // 55296 B

  const int tid = threadIdx.x;
  const int lane = tid & 63;
  const int wave = tid >> 6;                 // 0..3 = output d-slice
  const int q = lane >> 4, n = lane & 15;

  const unsigned short* xb = xcl + (size_t)b * V3 * 32;
  STAGE14(xb + ((size_t)((d * 48 + h) * 48 + w)) * 32 + pp * 8);

  f32x4 acc[6][4];
#pragma unroll
  for (int g = 0; g < 6; ++g)
#pragma unroll
    for (int mt = 0; mt < 4; ++mt) acc[g][mt] = (f32x4){0.f, 0.f, 0.f, 0.f};

  const unsigned short* wb = w1 + (size_t)b * 55296 + lane * 8;

  WAIT_VM(4);            // group A (planes 0..3) resident; B still in flight
  __builtin_amdgcn_s_barrier();
  COMPUTE_DZ(0, wb);     // dz=0 touches only planes 0..3
  WAIT_VM(0);
  __builtin_amdgcn_s_barrier();
  COMPUTE_DZ(1, wb);
  COMPUTE_DZ(2, wb);

  const int cls = y[b];
  const int od = d0 + wave, ow = w0 + n;
#pragma unroll
  for (int g = 0; g < 6; ++g) {
    const int oh = h0 + g;
    const size_t vg = (size_t)(od * 48 + oh) * 48 + ow;
#pragma unroll
    for (int mt = 0; mt < 4; ++mt) {
      const int c0 = mt * 16 + q * 4;
      ushort4 pk;
      pk.x = f2bf(fmaxf(acc[g][mt][0] + bsh[cls * 64 + c0 + 0], 0.f));
      pk.y = f2bf(fmaxf(acc[g][mt][1] + bsh[cls * 64 + c0 + 1], 0.f));
      pk.z = f2bf(fmaxf(acc[g][mt][2] + bsh[cls * 64 + c0 + 2], 0.f));
      pk.w = f2bf(fmaxf(acc[g][mt][3] + bsh[cls * 64 + c0 + 3], 0.f));
      *reinterpret_cast<ushort4*>(&actv[((size_t)b * V3 + vg) * 64 + c0]) = pk;
    }
  }
}

// ---------------------------------------------------------------- conv2 ----
// gamma/beta = conv3x3x3(actv; 64->32 each, stacked 64 couts), fused epilogue
// out = (x-mu)*rstd*(1+gamma) + beta.  2 kc passes over cin halves.
__global__ __launch_bounds__(256, 2)
void conv2_kernel(const unsigned short* __restrict__ actv,
                  const unsigned short* __restrict__ w23,
                  const int* __restrict__ y, const float* __restrict__ bgm,
                  const float* __restrict__ bbt, const float* __restrict__ x,
                  const float* __restrict__ mu, const float* __restrict__ rstd,
                  float* __restrict__ out, const float4* __restrict__ zpage) {
  const int d0 = (blockIdx.y >> 3) * 4;
  const int h0 = (blockIdx.y & 7) * 6;
  const int w0 = blockIdx.x * 16;
  const int b = blockIdx.z;

  __shared__ unsigned short lds[3456 * 8];   // 55296 B

  const int tid = threadIdx.x;
  const int lane = tid & 63;
  const int wave = tid >> 6;
  const int q = lane >> 4, n = lane & 15;

  f32x4 acc[6][4];
#pragma unroll
  for (int g = 0; g < 6; ++g)
#pragma unroll
    for (int mt = 0; mt < 4; ++mt) acc[g][mt] = (f32x4){0.f, 0.f, 0.f, 0.f};

  const unsigned short* ab = actv + (size_t)b * V3 * 64;

  for (int kc = 0; kc < 2; ++kc) {
    if (kc) { __syncthreads(); }   // all reads of pass-0 LDS retired
    STAGE14(ab + ((size_t)((d * 48 + h) * 48 + w)) * 64 + kc * 32 + pp * 8);

    const unsigned short* wb =
        w23 + (size_t)b * 110592 + (size_t)kc * 55296 + lane * 8;

    WAIT_VM(4);
    __builtin_amdgcn_s_barrier();
    COMPUTE_DZ(0, wb);
    WAIT_VM(0);
    __builtin_amdgcn_s_barrier();
    COMPUTE_DZ(1, wb);
    COMPUTE_DZ(2, wb);
  }

  const int cls = y[b];
  const int od = d0 + wave, ow = w0 + n;
#pragma unroll
  for (int g = 0; g < 6; ++g) {
    const int oh = h0 + g;
    const size_t vg = (size_t)(od * 48 + oh) * 48 + ow;
#pragma unroll
    for (int mt = 0; mt < 2; ++mt) {
#pragma unroll
      for (int r = 0; r < 4; ++r) {
        const int c = mt * 16 + q * 4 + r;
        const float gamma = acc[g][mt][r] + bgm[cls * 32 + c];
        const float beta = acc[g][mt + 2][r] + bbt[cls * 32 + c];
        const size_t xi = (size_t)(b * 32 + c) * V3 + vg;
        const float xn = (x[xi] - mu[b * 32 + c]) * rstd[b * 32 + c];
        out[xi] = xn * (1.f + gamma) + beta;
      }
    }
  }
}

// ------------------------------------------------------------------ launch -
extern "C" void kernel_launch(void* const* d_in, const int* in_sizes, int n_in,
                              void* d_out, int out_size, void* d_ws, size_t ws_size,
                              hipStream_t stream) {
  const float* x = (const float*)d_in[0];
  const int* y = (const int*)d_in[1];
  const float* Wsh = (const float*)d_in[2];
  const float* bsh = (const float*)d_in[3];
  const float* Wg = (const float*)d_in[4];
  const float* bg = (const float*)d_in[5];
  const float* Wb = (const float*)d_in[6];
  const float* bb = (const float*)d_in[7];
  float* out = (float*)d_out;

  char* ws = (char*)d_ws;
  unsigned short* xcl  = (unsigned short*)(ws + 0);           // 56,623,104 B
  unsigned short* actv = (unsigned short*)(ws + 56623104);    // 113,246,208 B
  unsigned short* w1   = (unsigned short*)(ws + 169869312);   //    884,736 B
  unsigned short* w23  = (unsigned short*)(ws + 170754048);   //  1,769,472 B
  float* mu    = (float*)(ws + 172523520);                    //      1,024 B
  float* rstd  = (float*)(ws + 172524544);                    //      1,024 B
  float4* zpg  = (float4*)(ws + 172525568);                   //      1,024 B

  stats_kernel<<<256, 1024, 0, stream>>>(x, mu, rstd, zpg);
  repack_kernel<<<BATCH * 48 * 48, 256, 0, stream>>>(x, xcl);
  wprep_kernel<<<(BATCH * 27 * 4 * 64 * 8 * 3 + 255) / 256, 256, 0, stream>>>(
      y, Wsh, Wg, Wb, w1, w23);

  dim3 grid(3, 96, BATCH);   // w:3, (d:12 x h:8):96, b:8
  conv1_kernel<<<grid, 256, 0, stream>>>(xcl, w1, y, bsh, actv, zpg);
  conv2_kernel<<<grid, 256, 0, stream>>>(actv, w23, y, bg, bb, x, mu, rstd, out, zpg);
}

// Round 6
// 610.829 us; speedup vs baseline: 2.2232x; 1.0600x over previous
//
#include <hip/hip_runtime.h>
#include <stdint.h>

#define V3 (48*48*48)   // 110592 voxels per channel
#define BATCH 8

typedef __bf16 bf16x8 __attribute__((ext_vector_type(8)));
typedef float  f32x4  __attribute__((ext_vector_type(4)));

__device__ __forceinline__ unsigned short f2bf(float f) {
  uint32_t u = __float_as_uint(f);
  u += 0x7fffu + ((u >> 16) & 1u);   // round-to-nearest-even
  return (unsigned short)(u >> 16);
}

// async 16B global->LDS; LDS dest = wave-uniform base + lane*16
#define GLDS16(gp, lp)                                                         \
  __builtin_amdgcn_global_load_lds(                                            \
      (const __attribute__((address_space(1))) void*)(gp),                     \
      (__attribute__((address_space(3))) void*)(lp), 16, 0, 0)

// ---------------------------------------------------------------- stats ----
// one block per (b,c): mu, rstd over 48^3; block 0 also zeroes the zero page.
__global__ __launch_bounds__(1024)
void stats_kernel(const float* __restrict__ x, float* __restrict__ mu,
                  float* __restrict__ rstd, float4* __restrict__ zpage) {
  if (blockIdx.x == 0 && threadIdx.x < 64) {
    float4 z; z.x = 0.f; z.y = 0.f; z.z = 0.f; z.w = 0.f;
    zpage[threadIdx.x] = z;
  }
  const int bc = blockIdx.x;  // 0..255
  const float4* p = reinterpret_cast<const float4*>(x + (size_t)bc * V3);
  float s = 0.f, s2 = 0.f;
  for (int i = threadIdx.x; i < V3 / 4; i += 1024) {   // 27 exact iterations
    float4 v = p[i];
    s  += (v.x + v.y) + (v.z + v.w);
    s2 += (v.x * v.x + v.y * v.y) + (v.z * v.z + v.w * v.w);
  }
  for (int o = 32; o; o >>= 1) { s += __shfl_down(s, o); s2 += __shfl_down(s2, o); }
  __shared__ float red[32];
  const int wave = threadIdx.x >> 6, lane = threadIdx.x & 63;
  if (lane == 0) { red[wave] = s; red[16 + wave] = s2; }
  __syncthreads();
  if (threadIdx.x == 0) {
    float S1 = 0.f, S2 = 0.f;
#pragma unroll
    for (int i = 0; i < 16; ++i) { S1 += red[i]; S2 += red[16 + i]; }
    float m = S1 / (float)V3;
    float var = S2 / (float)V3 - m * m;
    mu[bc] = m;
    rstd[bc] = rsqrtf(var + 1e-5f);
  }
}

// --------------------------------------------------------------- repack ----
// x [b][c][d][h][w] fp32 -> xcl [b][d][h][w][c] bf16 (channels-last)
__global__ __launch_bounds__(256)
void repack_kernel(const float* __restrict__ x, unsigned short* __restrict__ xcl) {
  const int bid = blockIdx.x;            // B*48*48 blocks, one (b,d,h) row each
  const int h = bid % 48;
  const int d = (bid / 48) % 48;
  const int b = bid / (48 * 48);
  __shared__ float tile[32][48];
  const float* src = x + (size_t)b * 32 * V3 + (size_t)(d * 48 + h) * 48;
  for (int i = threadIdx.x; i < 32 * 48; i += 256) {
    int c = i / 48, w = i - c * 48;
    tile[c][w] = src[(size_t)c * V3 + w];
  }
  __syncthreads();
  const int i = threadIdx.x;
  if (i < 48 * 4) {
    const int w = i >> 2, pp = i & 3;
    alignas(16) unsigned short pk[8];
#pragma unroll
    for (int j = 0; j < 8; ++j) pk[j] = f2bf(tile[pp * 8 + j][w]);
    *reinterpret_cast<uint4*>(
        &xcl[((size_t)b * V3 + (size_t)(d * 48 + h) * 48 + w) * 32 + pp * 8]) =
        *reinterpret_cast<const uint4*>(pk);
  }
}

// ---------------------------------------------------------------- wprep ----
// w1 : [b][tap(27)][mt(4)][lane(64)][8]   lane=(q*16+n) -> cout=mt*16+n, cin=q*8+j
// w23: [b][kc(2)][tap(27)][mt(4)][lane(64)][8]  cout rows 0-31 gamma, 32-63 beta
__global__ __launch_bounds__(256)
void wprep_kernel(const int* __restrict__ y, const float* __restrict__ Wsh,
                  const float* __restrict__ Wg, const float* __restrict__ Wb,
                  unsigned short* __restrict__ w1, unsigned short* __restrict__ w23) {
  const int N1 = BATCH * 27 * 4 * 64 * 8;       // 442368
  const int N2 = BATCH * 2 * 27 * 4 * 64 * 8;   // 884736
  int idx = blockIdx.x * 256 + threadIdx.x;
  if (idx < N1) {
    const int j = idx & 7;
    const int lane = (idx >> 3) & 63;
    const int mt = (idx >> 9) & 3;
    const int tap = (idx >> 11) % 27;
    const int b = idx / (27 << 11);
    const int q = lane >> 4, n = lane & 15;
    const int cout = mt * 16 + n, cin = q * 8 + j;
    const int cls = y[b];
    w1[idx] = f2bf(Wsh[((size_t)((cls * 64 + cout) * 32 + cin)) * 27 + tap]);
  } else if (idx < N1 + N2) {
    const int t = idx - N1;
    const int b = t / 110592;
    const int r1 = t - b * 110592;
    const int kc = r1 / 55296;
    const int r2 = r1 - kc * 55296;
    const int tap = r2 >> 11;
    const int r3 = r2 & 2047;
    const int mt = r3 >> 9;
    const int lane = (r3 >> 3) & 63;
    const int j = r3 & 7;
    const int q = lane >> 4, n = lane & 15;
    const int cout = mt * 16 + n, cin = kc * 32 + q * 8 + j;
    const int cls = y[b];
    float v = (cout < 32) ? Wg[((size_t)((cls * 32 + cout) * 64 + cin)) * 27 + tap]
                          : Wb[((size_t)((cls * 32 + (cout - 32)) * 64 + cin)) * 27 + tap];
    w23[t] = f2bf(v);
  }
}

// ------------------------------------------------------- conv tile geometry -
// Tile 4d x 6h x 16w, 4 waves (256 thr), wave = output d-slice.
// __launch_bounds__(256,2), 55296B LDS, 2 blocks/CU — R0's proven reg budget.
// Halo 6d x 8h x 18w = 864 voxels; LDS PLANE-MAJOR, 16B chunks:
//   slot(ld,pp,lh,lw) = ((ld*4+pp)*8+lh)*18 + lw         (3456 slots)
// Planes 0..3 = slots [0,2304) = staging k 0..8 exactly (j = tid + 256k).
// Planes 4..5 = k 9..13 (k=13 only tid<128); per-wave B counts {5,5,4,4}.
// sched_barrier(0) pins group-A VMEM issue first; vmem ops retire in order,
// so WAIT_VM(8) (post-A in-flight <= B(5)+weights(4)=9) retires all of A,
// and WAIT_VM(4) at barrier 2 retires all B while chunk-1's tap-9 weight
// prefetch (the 4 newest ops) stays in flight.

#define STAGE_K(K0, K1, SRC_EXPR)                                              \
  do {                                                                         \
    _Pragma("unroll") for (int k = (K0); k < (K1); ++k) {                      \
      const int j = tid + k * 256;                                             \
      if (k < 13 || tid < 128) {                                               \
        const int ld_ = j / 576;                                               \
        const int r = j - ld_ * 576;                                           \
        const int pp = r / 144;                                                \
        const int r2 = r - pp * 144;                                           \
        const int lh = r2 / 18;                                                \
        const int lw = r2 - lh * 18;                                           \
        const int d = d0 + ld_ - 1, h = h0 + lh - 1, w = w0 + lw - 1;          \
        const bool ok = (unsigned)d < 48u && (unsigned)h < 48u && (unsigned)w < 48u; \
        const void* gp = ok ? (const void*)(SRC_EXPR)                          \
                            : (const void*)((const char*)zpage + lane * 16);   \
        GLDS16(gp, &lds[(size_t)(j - lane) * 8]);                              \
      }                                                                        \
    }                                                                          \
  } while (0)

#define STAGE14(SRC_EXPR)                                                      \
  do {                                                                         \
    STAGE_K(0, 9, SRC_EXPR);                                                   \
    __builtin_amdgcn_sched_barrier(0);  /* pin group A before group B */       \
    STAGE_K(9, 14, SRC_EXPR);                                                  \
  } while (0)

#define WAIT_VM(N)                                                             \
  asm volatile("s_waitcnt vmcnt(" #N ")" ::: "memory")

// Rolled tap chunk [T0,T1), T1 <= 26: ALWAYS prefetches tap+1 (valid index).
// 2-deep weight double-buffer; reg-safe (R0 form); unroll 1 = spill guard.
#define COMPUTE_TAPS_PF(T0, T1, WB)                                            \
  do {                                                                         \
    __builtin_amdgcn_s_setprio(1);                                             \
    _Pragma("unroll 1") for (int tap = (T0); tap < (T1); ++tap) {              \
      bf16x8 anxt[4];                                                          \
      _Pragma("unroll") for (int mt = 0; mt < 4; ++mt)                         \
        anxt[mt] = *reinterpret_cast<const bf16x8*>(                           \
            &(WB)[((tap + 1) * 4 + mt) * 512]);                                \
      const int dz_ = tap / 9, rr_ = tap - dz_ * 9;                            \
      const int dy_ = rr_ / 3, dx_ = rr_ - dy_ * 3;                            \
      const int vb_ = ((wave + dz_) * 4 + q) * 144 + n + dy_ * 18 + dx_;       \
      bf16x8 bf[6];                                                            \
      _Pragma("unroll") for (int g = 0; g < 6; ++g)                            \
        bf[g] = *reinterpret_cast<const bf16x8*>(&lds[(size_t)(vb_ + g * 18) * 8]); \
      _Pragma("unroll") for (int g = 0; g < 6; ++g)                            \
        _Pragma("unroll") for (int mt = 0; mt < 4; ++mt)                       \
          acc[g][mt] = __builtin_amdgcn_mfma_f32_16x16x32_bf16(                \
              acur[mt], bf[g], acc[g][mt], 0, 0, 0);                           \
      _Pragma("unroll") for (int mt = 0; mt < 4; ++mt) acur[mt] = anxt[mt];    \
    }                                                                          \
    __builtin_amdgcn_s_setprio(0);                                             \
  } while (0)

// Peeled final tap (26: dz=2,dy=2,dx=2): no prefetch, no rotation.
#define COMPUTE_TAP26()                                                        \
  do {                                                                         \
    __builtin_amdgcn_s_setprio(1);                                             \
    const int vb_ = ((wave + 2) * 4 + q) * 144 + n + 2 * 18 + 2;               \
    bf16x8 bf[6];                                                              \
    _Pragma("unroll") for (int g = 0; g < 6; ++g)                              \
      bf[g] = *reinterpret_cast<const bf16x8*>(&lds[(size_t)(vb_ + g * 18) * 8]); \
    _Pragma("unroll") for (int g = 0; g < 6; ++g)                              \
      _Pragma("unroll") for (int mt = 0; mt < 4; ++mt)                         \
        acc[g][mt] = __builtin_amdgcn_mfma_f32_16x16x32_bf16(                  \
            acur[mt], bf[g], acc[g][mt], 0, 0, 0);                             \
    __builtin_amdgcn_s_setprio(0);                                             \
  } while (0)

// ---------------------------------------------------------------- conv1 ----
// actv = relu(conv3x3x3(x; 32->64)), channels-last bf16 out.
__global__ __launch_bounds__(256, 2)
void conv1_kernel(const unsigned short* __restrict__ xcl,
                  const unsigned short* __restrict__ w1,
                  const int* __restrict__ y, const float* __restrict__ bsh,
                  unsigned short* __restrict__ actv,
                  const float4* __restrict__ zpage) {
  const int d0 = (blockIdx.y >> 3) * 4;
  const int h0 = (blockIdx.y & 7) * 6;
  const int w0 = blockIdx.x * 16;
  const int b = blockIdx.z;

  __shared__ unsigned short lds[3456 * 8];   // 55296 B

  const int tid = threadIdx.x;
  const int lane = tid & 63;
  const int wave = tid >> 6;                 // 0..3 = output d-slice
  const int q = lane >> 4, n = lane & 15;

  const unsigned short* xb = xcl + (size_t)b * V3 * 32;
  STAGE14(xb + ((size_t)((d * 48 + h) * 48 + w)) * 32 + pp * 8);

  // preload tap-0 weights: in flight during the barrier wait
  const unsigned short* wb = w1 + (size_t)b * 55296 + lane * 8;
  bf16x8 acur[4];
#pragma unroll
  for (int mt = 0; mt < 4; ++mt)
    acur[mt] = *reinterpret_cast<const bf16x8*>(&wb[mt * 512]);

  f32x4 acc[6][4];
#pragma unroll
  for (int g = 0; g < 6; ++g)
#pragma unroll
    for (int mt = 0; mt < 4; ++mt) acc[g][mt] = (f32x4){0.f, 0.f, 0.f, 0.f};

  WAIT_VM(8);            // all 9 group-A staging loads resident
  __builtin_amdgcn_s_barrier();
  COMPUTE_TAPS_PF(0, 9, wb);    // dz=0: planes 0..3 only; prefetches tap 9
  WAIT_VM(4);            // B staging resident; tap-9 weights stay in flight
  __builtin_amdgcn_s_barrier();
  COMPUTE_TAPS_PF(9, 26, wb);
  COMPUTE_TAP26();

  const int cls = y[b];
  const int od = d0 + wave, ow = w0 + n;
#pragma unroll
  for (int g = 0; g < 6; ++g) {
    const int oh = h0 + g;
    const size_t vg = (size_t)(od * 48 + oh) * 48 + ow;
#pragma unroll
    for (int mt = 0; mt < 4; ++mt) {
      const int c0 = mt * 16 + q * 4;
      ushort4 pk;
      pk.x = f2bf(fmaxf(acc[g][mt][0] + bsh[cls * 64 + c0 + 0], 0.f));
      pk.y = f2bf(fmaxf(acc[g][mt][1] + bsh[cls * 64 + c0 + 1], 0.f));
      pk.z = f2bf(fmaxf(acc[g][mt][2] + bsh[cls * 64 + c0 + 2], 0.f));
      pk.w = f2bf(fmaxf(acc[g][mt][3] + bsh[cls * 64 + c0 + 3], 0.f));
      *reinterpret_cast<ushort4*>(&actv[((size_t)b * V3 + vg) * 64 + c0]) = pk;
    }
  }
}

// ---------------------------------------------------------------- conv2 ----
// gamma/beta = conv3x3x3(actv; 64->32 each, stacked 64 couts), fused epilogue
// out = (x-mu)*rstd*(1+gamma) + beta.  2 kc passes over cin halves.
__global__ __launch_bounds__(256, 2)
void conv2_kernel(const unsigned short* __restrict__ actv,
                  const unsigned short* __restrict__ w23,
                  const int* __restrict__ y, const float* __restrict__ bgm,
                  const float* __restrict__ bbt, const float* __restrict__ x,
                  const float* __restrict__ mu, const float* __restrict__ rstd,
                  float* __restrict__ out, const float4* __restrict__ zpage) {
  const int d0 = (blockIdx.y >> 3) * 4;
  const int h0 = (blockIdx.y & 7) * 6;
  const int w0 = blockIdx.x * 16;
  const int b = blockIdx.z;

  __shared__ unsigned short lds[3456 * 8];   // 55296 B

  const int tid = threadIdx.x;
  const int lane = tid & 63;
  const int wave = tid >> 6;
  const int q = lane >> 4, n = lane & 15;

  f32x4 acc[6][4];
#pragma unroll
  for (int g = 0; g < 6; ++g)
#pragma unroll
    for (int mt = 0; mt < 4; ++mt) acc[g][mt] = (f32x4){0.f, 0.f, 0.f, 0.f};

  const unsigned short* ab = actv + (size_t)b * V3 * 64;

  for (int kc = 0; kc < 2; ++kc) {
    if (kc) { __syncthreads(); }   // all reads of pass-0 LDS retired
    STAGE14(ab + ((size_t)((d * 48 + h) * 48 + w)) * 64 + kc * 32 + pp * 8);

    const unsigned short* wb =
        w23 + (size_t)b * 110592 + (size_t)kc * 55296 + lane * 8;
    bf16x8 acur[4];
#pragma unroll
    for (int mt = 0; mt < 4; ++mt)
      acur[mt] = *reinterpret_cast<const bf16x8*>(&wb[mt * 512]);

    WAIT_VM(8);
    __builtin_amdgcn_s_barrier();
    COMPUTE_TAPS_PF(0, 9, wb);
    WAIT_VM(4);
    __builtin_amdgcn_s_barrier();
    COMPUTE_TAPS_PF(9, 26, wb);
    COMPUTE_TAP26();
  }

  const int cls = y[b];
  const int od = d0 + wave, ow = w0 + n;
#pragma unroll
  for (int g = 0; g < 6; ++g) {
    const int oh = h0 + g;
    const size_t vg = (size_t)(od * 48 + oh) * 48 + ow;
#pragma unroll
    for (int mt = 0; mt < 2; ++mt) {
#pragma unroll
      for (int r = 0; r < 4; ++r) {
        const int c = mt * 16 + q * 4 + r;
        const float gamma = acc[g][mt][r] + bgm[cls * 32 + c];
        const float beta = acc[g][mt + 2][r] + bbt[cls * 32 + c];
        const size_t xi = (size_t)(b * 32 + c) * V3 + vg;
        const float xn = (x[xi] - mu[b * 32 + c]) * rstd[b * 32 + c];
        out[xi] = xn * (1.f + gamma) + beta;
      }
    }
  }
}

// ------------------------------------------------------------------ launch -
extern "C" void kernel_launch(void* const* d_in, const int* in_sizes, int n_in,
                              void* d_out, int out_size, void* d_ws, size_t ws_size,
                              hipStream_t stream) {
  const float* x = (const float*)d_in[0];
  const int* y = (const int*)d_in[1];
  const float* Wsh = (const float*)d_in[2];
  const float* bsh = (const float*)d_in[3];
  const float* Wg = (const float*)d_in[4];
  const float* bg = (const float*)d_in[5];
  const float* Wb = (const float*)d_in[6];
  const float* bb = (const float*)d_in[7];
  float* out = (float*)d_out;

  char* ws = (char*)d_ws;
  unsigned short* xcl  = (unsigned short*)(ws + 0);           // 56,623,104 B
  unsigned short* actv = (unsigned short*)(ws + 56623104);    // 113,246,208 B
  unsigned short* w1   = (unsigned short*)(ws + 169869312);   //    884,736 B
  unsigned short* w23  = (unsigned short*)(ws + 170754048);   //  1,769,472 B
  float* mu    = (float*)(ws + 172523520);                    //      1,024 B
  float* rstd  = (float*)(ws + 172524544);                    //      1,024 B
  float4* zpg  = (float4*)(ws + 172525568);                   //      1,024 B

  stats_kernel<<<256, 1024, 0, stream>>>(x, mu, rstd, zpg);
  repack_kernel<<<BATCH * 48 * 48, 256, 0, stream>>>(x, xcl);
  wprep_kernel<<<(BATCH * 27 * 4 * 64 * 8 * 3 + 255) / 256, 256, 0, stream>>>(
      y, Wsh, Wg, Wb, w1, w23);

  dim3 grid(3, 96, BATCH);   // w:3, (d:12 x h:8):96, b:8
  conv1_kernel<<<grid, 256, 0, stream>>>(xcl, w1, y, bsh, actv, zpg);
  conv2_kernel<<<grid, 256, 0, stream>>>(actv, w23, y, bg, bb, x, mu, rstd, out, zpg);
}

// Round 7
// 593.571 us; speedup vs baseline: 2.2878x; 1.0291x over previous
//
#include <hip/hip_runtime.h>
#include <stdint.h>

#define V3 (48*48*48)   // 110592 voxels per channel
#define BATCH 8

typedef __bf16 bf16x8 __attribute__((ext_vector_type(8)));
typedef float  f32x4  __attribute__((ext_vector_type(4)));

__device__ __forceinline__ unsigned short f2bf(float f) {
  uint32_t u = __float_as_uint(f);
  u += 0x7fffu + ((u >> 16) & 1u);   // round-to-nearest-even
  return (unsigned short)(u >> 16);
}

// async 16B global->LDS; LDS dest = wave-uniform base + lane*16
#define GLDS16(gp, lp)                                                         \
  __builtin_amdgcn_global_load_lds(                                            \
      (const __attribute__((address_space(1))) void*)(gp),                     \
      (__attribute__((address_space(3))) void*)(lp), 16, 0, 0)

// ---------------------------------------------------------------- stats ----
// one block per (b,c): mu, rstd over 48^3; block 0 also zeroes the zero page.
__global__ __launch_bounds__(1024)
void stats_kernel(const float* __restrict__ x, float* __restrict__ mu,
                  float* __restrict__ rstd, float4* __restrict__ zpage) {
  if (blockIdx.x == 0 && threadIdx.x < 64) {
    float4 z; z.x = 0.f; z.y = 0.f; z.z = 0.f; z.w = 0.f;
    zpage[threadIdx.x] = z;
  }
  const int bc = blockIdx.x;  // 0..255
  const float4* p = reinterpret_cast<const float4*>(x + (size_t)bc * V3);
  float s = 0.f, s2 = 0.f;
  for (int i = threadIdx.x; i < V3 / 4; i += 1024) {   // 27 exact iterations
    float4 v = p[i];
    s  += (v.x + v.y) + (v.z + v.w);
    s2 += (v.x * v.x + v.y * v.y) + (v.z * v.z + v.w * v.w);
  }
  for (int o = 32; o; o >>= 1) { s += __shfl_down(s, o); s2 += __shfl_down(s2, o); }
  __shared__ float red[32];
  const int wave = threadIdx.x >> 6, lane = threadIdx.x & 63;
  if (lane == 0) { red[wave] = s; red[16 + wave] = s2; }
  __syncthreads();
  if (threadIdx.x == 0) {
    float S1 = 0.f, S2 = 0.f;
#pragma unroll
    for (int i = 0; i < 16; ++i) { S1 += red[i]; S2 += red[16 + i]; }
    float m = S1 / (float)V3;
    float var = S2 / (float)V3 - m * m;
    mu[bc] = m;
    rstd[bc] = rsqrtf(var + 1e-5f);
  }
}

// --------------------------------------------------------------- repack ----
// x [b][c][d][h][w] fp32 -> xcl [b][d][h][w][c] bf16 (channels-last)
__global__ __launch_bounds__(256)
void repack_kernel(const float* __restrict__ x, unsigned short* __restrict__ xcl) {
  const int bid = blockIdx.x;            // B*48*48 blocks, one (b,d,h) row each
  const int h = bid % 48;
  const int d = (bid / 48) % 48;
  const int b = bid / (48 * 48);
  __shared__ float tile[32][48];
  const float* src = x + (size_t)b * 32 * V3 + (size_t)(d * 48 + h) * 48;
  for (int i = threadIdx.x; i < 32 * 48; i += 256) {
    int c = i / 48, w = i - c * 48;
    tile[c][w] = src[(size_t)c * V3 + w];
  }
  __syncthreads();
  const int i = threadIdx.x;
  if (i < 48 * 4) {
    const int w = i >> 2, pp = i & 3;
    alignas(16) unsigned short pk[8];
#pragma unroll
    for (int j = 0; j < 8; ++j) pk[j] = f2bf(tile[pp * 8 + j][w]);
    *reinterpret_cast<uint4*>(
        &xcl[((size_t)b * V3 + (size_t)(d * 48 + h) * 48 + w) * 32 + pp * 8]) =
        *reinterpret_cast<const uint4*>(pk);
  }
}

// ---------------------------------------------------------------- wprep ----
// w1 : [b][tap(27)][mt(4)][lane(64)][8]   lane=(q*16+n) -> cout=mt*16+n, cin=q*8+j
// w23: [b][kc(2)][tap(27)][mt(4)][lane(64)][8]  cout rows 0-31 gamma, 32-63 beta
__global__ __launch_bounds__(256)
void wprep_kernel(const int* __restrict__ y, const float* __restrict__ Wsh,
                  const float* __restrict__ Wg, const float* __restrict__ Wb,
                  unsigned short* __restrict__ w1, unsigned short* __restrict__ w23) {
  const int N1 = BATCH * 27 * 4 * 64 * 8;       // 442368
  const int N2 = BATCH * 2 * 27 * 4 * 64 * 8;   // 884736
  int idx = blockIdx.x * 256 + threadIdx.x;
  if (idx < N1) {
    const int j = idx & 7;
    const int lane = (idx >> 3) & 63;
    const int mt = (idx >> 9) & 3;
    const int tap = (idx >> 11) % 27;
    const int b = idx / (27 << 11);
    const int q = lane >> 4, n = lane & 15;
    const int cout = mt * 16 + n, cin = q * 8 + j;
    const int cls = y[b];
    w1[idx] = f2bf(Wsh[((size_t)((cls * 64 + cout) * 32 + cin)) * 27 + tap]);
  } else if (idx < N1 + N2) {
    const int t = idx - N1;
    const int b = t / 110592;
    const int r1 = t - b * 110592;
    const int kc = r1 / 55296;
    const int r2 = r1 - kc * 55296;
    const int tap = r2 >> 11;
    const int r3 = r2 & 2047;
    const int mt = r3 >> 9;
    const int lane = (r3 >> 3) & 63;
    const int j = r3 & 7;
    const int q = lane >> 4, n = lane & 15;
    const int cout = mt * 16 + n, cin = kc * 32 + q * 8 + j;
    const int cls = y[b];
    float v = (cout < 32) ? Wg[((size_t)((cls * 32 + cout) * 64 + cin)) * 27 + tap]
                          : Wb[((size_t)((cls * 32 + (cout - 32)) * 64 + cin)) * 27 + tap];
    w23[t] = f2bf(v);
  }
}

// ------------------------------------------------------- conv tile geometry -
// Tile 4d x 4h x 16w, 4 waves (256 thr), wave = output d-slice.
// Halo 6d x 6h x 18w = 648 voxels; LDS PLANE-MAJOR, 16B chunks:
//   slot(ld,pp,lh,lw) = ((ld*4+pp)*6+lh)*18 + lw         (2592 slots, 41472 B)
// Occupancy: LDS 160K/41.5K -> 3 blocks/CU; acc[4][4]=64 regs (was 96) so
// total unified regfile ~150/wave fits the (256,3) cap of 170 -> 12 waves/CU
// (was 8). This is the round's lever: +50% TLP at unchanged schedule.
// Staging: 11 instrs/wave, slot j = tid + 256k, k=0..10 (k=10 only tid<32).
// Group A = k0..6 (slots 0..1791) covers planes 0..3 (0..1727) = all dz=0
// needs; group B = k7..10, per-wave counts {4,3,3,3}; weights preloaded after.
// Barrier 1 WAIT_VM(7): keep newest B+W(<=7) -> all A retired for every wave.
// Barrier 2 WAIT_VM(4): tap-9 weight prefetch (4 newest) stays in flight.

#define STAGE_K(K0, K1, SRC_EXPR)                                              \
  do {                                                                         \
    _Pragma("unroll") for (int k = (K0); k < (K1); ++k) {                      \
      const int j = tid + k * 256;                                             \
      if (k < 10 || tid < 32) {                                                \
        const int ld_ = j / 432;                                               \
        const int r = j - ld_ * 432;                                           \
        const int pp = r / 108;                                                \
        const int r2 = r - pp * 108;                                           \
        const int lh = r2 / 18;                                                \
        const int lw = r2 - lh * 18;                                           \
        const int d = d0 + ld_ - 1, h = h0 + lh - 1, w = w0 + lw - 1;          \
        const bool ok = (unsigned)d < 48u && (unsigned)h < 48u && (unsigned)w < 48u; \
        const void* gp = ok ? (const void*)(SRC_EXPR)                          \
                            : (const void*)((const char*)zpage + lane * 16);   \
        GLDS16(gp, &lds[(size_t)(j - lane) * 8]);                              \
      }                                                                        \
    }                                                                          \
  } while (0)

#define STAGE11(SRC_EXPR)                                                      \
  do {                                                                         \
    STAGE_K(0, 7, SRC_EXPR);                                                   \
    __builtin_amdgcn_sched_barrier(0);  /* pin group A before group B */       \
    STAGE_K(7, 11, SRC_EXPR);                                                  \
  } while (0)

#define WAIT_VM(N)                                                             \
  asm volatile("s_waitcnt vmcnt(" #N ")" ::: "memory")

// Rolled tap chunk [T0,T1), T1 <= 26: ALWAYS prefetches tap+1 (valid index).
// 2-deep weight double-buffer; unroll 1 = spill guard.
#define COMPUTE_TAPS_PF(T0, T1, WB)                                            \
  do {                                                                         \
    __builtin_amdgcn_s_setprio(1);                                             \
    _Pragma("unroll 1") for (int tap = (T0); tap < (T1); ++tap) {              \
      bf16x8 anxt[4];                                                          \
      _Pragma("unroll") for (int mt = 0; mt < 4; ++mt)                         \
        anxt[mt] = *reinterpret_cast<const bf16x8*>(                           \
            &(WB)[((tap + 1) * 4 + mt) * 512]);                                \
      const int dz_ = tap / 9, rr_ = tap - dz_ * 9;                            \
      const int dy_ = rr_ / 3, dx_ = rr_ - dy_ * 3;                            \
      const int vb_ = ((wave + dz_) * 4 + q) * 108 + dy_ * 18 + dx_ + n;       \
      bf16x8 bf[4];                                                            \
      _Pragma("unroll") for (int g = 0; g < 4; ++g)                            \
        bf[g] = *reinterpret_cast<const bf16x8*>(&lds[(size_t)(vb_ + g * 18) * 8]); \
      _Pragma("unroll") for (int g = 0; g < 4; ++g)                            \
        _Pragma("unroll") for (int mt = 0; mt < 4; ++mt)                       \
          acc[g][mt] = __builtin_amdgcn_mfma_f32_16x16x32_bf16(                \
              acur[mt], bf[g], acc[g][mt], 0, 0, 0);                           \
      _Pragma("unroll") for (int mt = 0; mt < 4; ++mt) acur[mt] = anxt[mt];    \
    }                                                                          \
    __builtin_amdgcn_s_setprio(0);                                             \
  } while (0)

// Peeled final tap (26: dz=2,dy=2,dx=2): no prefetch, no rotation.
#define COMPUTE_TAP26()                                                        \
  do {                                                                         \
    __builtin_amdgcn_s_setprio(1);                                             \
    const int vb_ = ((wave + 2) * 4 + q) * 108 + 2 * 18 + 2 + n;               \
    bf16x8 bf[4];                                                              \
    _Pragma("unroll") for (int g = 0; g < 4; ++g)                              \
      bf[g] = *reinterpret_cast<const bf16x8*>(&lds[(size_t)(vb_ + g * 18) * 8]); \
    _Pragma("unroll") for (int g = 0; g < 4; ++g)                              \
      _Pragma("unroll") for (int mt = 0; mt < 4; ++mt)                         \
        acc[g][mt] = __builtin_amdgcn_mfma_f32_16x16x32_bf16(                  \
            acur[mt], bf[g], acc[g][mt], 0, 0, 0);                             \
    __builtin_amdgcn_s_setprio(0);                                             \
  } while (0)

// ---------------------------------------------------------------- conv1 ----
// actv = relu(conv3x3x3(x; 32->64)), channels-last bf16 out.
__global__ __launch_bounds__(256, 3)
void conv1_kernel(const unsigned short* __restrict__ xcl,
                  const unsigned short* __restrict__ w1,
                  const int* __restrict__ y, const float* __restrict__ bsh,
                  unsigned short* __restrict__ actv,
                  const float4* __restrict__ zpage) {
  const int d0 = (blockIdx.y / 12) * 4;
  const int h0 = (blockIdx.y % 12) * 4;
  const int w0 = blockIdx.x * 16;
  const int b = blockIdx.z;

  __shared__ unsigned short lds[2592 * 8];   // 41472 B

  const int tid = threadIdx.x;
  const int lane = tid & 63;
  const int wave = tid >> 6;                 // 0..3 = output d-slice
  const int q = lane >> 4, n = lane & 15;

  const unsigned short* xb = xcl + (size_t)b * V3 * 32;
  STAGE11(xb + ((size_t)((d * 48 + h) * 48 + w)) * 32 + pp * 8);

  // preload tap-0 weights: in flight during the barrier wait
  const unsigned short* wb = w1 + (size_t)b * 55296 + lane * 8;
  bf16x8 acur[4];
#pragma unroll
  for (int mt = 0; mt < 4; ++mt)
    acur[mt] = *reinterpret_cast<const bf16x8*>(&wb[mt * 512]);
  __builtin_amdgcn_sched_barrier(0);   // pin weight preload before the wait

  f32x4 acc[4][4];
#pragma unroll
  for (int g = 0; g < 4; ++g)
#pragma unroll
    for (int mt = 0; mt < 4; ++mt) acc[g][mt] = (f32x4){0.f, 0.f, 0.f, 0.f};

  WAIT_VM(7);            // all 7 group-A staging instrs resident
  __builtin_amdgcn_s_barrier();
  COMPUTE_TAPS_PF(0, 9, wb);    // dz=0: planes 0..3 only; prefetches tap 9
  WAIT_VM(4);            // B staging resident; tap-9 weights stay in flight
  __builtin_amdgcn_s_barrier();
  COMPUTE_TAPS_PF(9, 26, wb);
  COMPUTE_TAP26();

  const int cls = y[b];
  const int od = d0 + wave, ow = w0 + n;
#pragma unroll
  for (int g = 0; g < 4; ++g) {
    const int oh = h0 + g;
    const size_t vg = (size_t)(od * 48 + oh) * 48 + ow;
#pragma unroll
    for (int mt = 0; mt < 4; ++mt) {
      const int c0 = mt * 16 + q * 4;
      ushort4 pk;
      pk.x = f2bf(fmaxf(acc[g][mt][0] + bsh[cls * 64 + c0 + 0], 0.f));
      pk.y = f2bf(fmaxf(acc[g][mt][1] + bsh[cls * 64 + c0 + 1], 0.f));
      pk.z = f2bf(fmaxf(acc[g][mt][2] + bsh[cls * 64 + c0 + 2], 0.f));
      pk.w = f2bf(fmaxf(acc[g][mt][3] + bsh[cls * 64 + c0 + 3], 0.f));
      *reinterpret_cast<ushort4*>(&actv[((size_t)b * V3 + vg) * 64 + c0]) = pk;
    }
  }
}

// ---------------------------------------------------------------- conv2 ----
// gamma/beta = conv3x3x3(actv; 64->32 each, stacked 64 couts), fused epilogue
// out = (x-mu)*rstd*(1+gamma) + beta.  2 kc passes over cin halves.
__global__ __launch_bounds__(256, 3)
void conv2_kernel(const unsigned short* __restrict__ actv,
                  const unsigned short* __restrict__ w23,
                  const int* __restrict__ y, const float* __restrict__ bgm,
                  const float* __restrict__ bbt, const float* __restrict__ x,
                  const float* __restrict__ mu, const float* __restrict__ rstd,
                  float* __restrict__ out, const float4* __restrict__ zpage) {
  const int d0 = (blockIdx.y / 12) * 4;
  const int h0 = (blockIdx.y % 12) * 4;
  const int w0 = blockIdx.x * 16;
  const int b = blockIdx.z;

  __shared__ unsigned short lds[2592 * 8];   // 41472 B

  const int tid = threadIdx.x;
  const int lane = tid & 63;
  const int wave = tid >> 6;
  const int q = lane >> 4, n = lane & 15;

  f32x4 acc[4][4];
#pragma unroll
  for (int g = 0; g < 4; ++g)
#pragma unroll
    for (int mt = 0; mt < 4; ++mt) acc[g][mt] = (f32x4){0.f, 0.f, 0.f, 0.f};

  const unsigned short* ab = actv + (size_t)b * V3 * 64;

  for (int kc = 0; kc < 2; ++kc) {
    if (kc) { __syncthreads(); }   // all reads of pass-0 LDS retired
    STAGE11(ab + ((size_t)((d * 48 + h) * 48 + w)) * 64 + kc * 32 + pp * 8);

    const unsigned short* wb =
        w23 + (size_t)b * 110592 + (size_t)kc * 55296 + lane * 8;
    bf16x8 acur[4];
#pragma unroll
    for (int mt = 0; mt < 4; ++mt)
      acur[mt] = *reinterpret_cast<const bf16x8*>(&wb[mt * 512]);
    __builtin_amdgcn_sched_barrier(0);   // pin weight preload before the wait

    WAIT_VM(7);
    __builtin_amdgcn_s_barrier();
    COMPUTE_TAPS_PF(0, 9, wb);
    WAIT_VM(4);
    __builtin_amdgcn_s_barrier();
    COMPUTE_TAPS_PF(9, 26, wb);
    COMPUTE_TAP26();
  }

  const int cls = y[b];
  const int od = d0 + wave, ow = w0 + n;
#pragma unroll
  for (int g = 0; g < 4; ++g) {
    const int oh = h0 + g;
    const size_t vg = (size_t)(od * 48 + oh) * 48 + ow;
#pragma unroll
    for (int mt = 0; mt < 2; ++mt) {
#pragma unroll
      for (int r = 0; r < 4; ++r) {
        const int c = mt * 16 + q * 4 + r;
        const float gamma = acc[g][mt][r] + bgm[cls * 32 + c];
        const float beta = acc[g][mt + 2][r] + bbt[cls * 32 + c];
        const size_t xi = (size_t)(b * 32 + c) * V3 + vg;
        const float xn = (x[xi] - mu[b * 32 + c]) * rstd[b * 32 + c];
        out[xi] = xn * (1.f + gamma) + beta;
      }
    }
  }
}

// ------------------------------------------------------------------ launch -
extern "C" void kernel_launch(void* const* d_in, const int* in_sizes, int n_in,
                              void* d_out, int out_size, void* d_ws, size_t ws_size,
                              hipStream_t stream) {
  const float* x = (const float*)d_in[0];
  const int* y = (const int*)d_in[1];
  const float* Wsh = (const float*)d_in[2];
  const float* bsh = (const float*)d_in[3];
  const float* Wg = (const float*)d_in[4];
  const float* bg = (const float*)d_in[5];
  const float* Wb = (const float*)d_in[6];
  const float* bb = (const float*)d_in[7];
  float* out = (float*)d_out;

  char* ws = (char*)d_ws;
  unsigned short* xcl  = (unsigned short*)(ws + 0);           // 56,623,104 B
  unsigned short* actv = (unsigned short*)(ws + 56623104);    // 113,246,208 B
  unsigned short* w1   = (unsigned short*)(ws + 169869312);   //    884,736 B
  unsigned short* w23  = (unsigned short*)(ws + 170754048);   //  1,769,472 B
  float* mu    = (float*)(ws + 172523520);                    //      1,024 B
  float* rstd  = (float*)(ws + 172524544);                    //      1,024 B
  float4* zpg  = (float4*)(ws + 172525568);                   //      1,024 B

  stats_kernel<<<256, 1024, 0, stream>>>(x, mu, rstd, zpg);
  repack_kernel<<<BATCH * 48 * 48, 256, 0, stream>>>(x, xcl);
  wprep_kernel<<<(BATCH * 27 * 4 * 64 * 8 * 3 + 255) / 256, 256, 0, stream>>>(
      y, Wsh, Wg, Wb, w1, w23);

  dim3 grid(3, 144, BATCH);   // w:3, (d:12 x h:12):144, b:8
  conv1_kernel<<<grid, 256, 0, stream>>>(xcl, w1, y, bsh, actv, zpg);
  conv2_kernel<<<grid, 256, 0, stream>>>(actv, w23, y, bg, bb, x, mu, rstd, out, zpg);
}